// Round 19
// baseline (565.480 us; speedup 1.0000x reference)
//
#include <hip/hip_runtime.h>
#include <math.h>

// CTRNN + adaptive DOPRI5 (B=2048, N=1024). Round 19 = Round 18 with the
// partner-staging latency hidden: in exch_gemm, poll immediately after the
// flag store (partners' copies are concurrent -> poll ~free), then ISSUE
// the 6 partner global_load_lds and run the OWN-quarter GEMM before the
// drain barrier (staging writes partner LDS regions; own GEMM reads the
// own region -> disjoint, WAR-free). One __syncthreads after the own GEMM
// drains vmcnt -> partner GEMMs see complete images. All else identical
// to r18 (256 blocks x 512 thr, 64 rowgroups x 4 col-quarters, quad
// partners same-XCD, y/ys in LDS, k's half2 regs, M=32 MFMA, packed-flag
// err exchange, redundant uniform controller, FSAL k1=k7).

typedef float f4 __attribute__((ext_vector_type(4)));
typedef float f32x4 __attribute__((ext_vector_type(4)));
typedef _Float16 half8v __attribute__((ext_vector_type(8)));
typedef _Float16 half2v __attribute__((ext_vector_type(2)));
typedef unsigned long long u64;

#define AS1 __attribute__((address_space(1)))
#define AS3 __attribute__((address_space(3)))

#define NBLK 256
#define NTHR 512

#define E1c (71.0f / 57600.0f)
#define E3c (-71.0f / 16695.0f)
#define E4c (71.0f / 1920.0f)
#define E5c (-17253.0f / 339200.0f)
#define E6c (22.0f / 525.0f)
#define E7c (-1.0f / 40.0f)

#define ALDI(p) __hip_atomic_load((p), __ATOMIC_ACQUIRE, __HIP_MEMORY_SCOPE_AGENT)
#define ASTI(p, v) __hip_atomic_store((p), (v), __ATOMIC_RELEASE, __HIP_MEMORY_SCOPE_AGENT)
#define ALD64(p) __hip_atomic_load((p), __ATOMIC_ACQUIRE, __HIP_MEMORY_SCOPE_AGENT)
#define AST64(p, v) __hip_atomic_store((p), (v), __ATOMIC_RELEASE, __HIP_MEMORY_SCOPE_AGENT)

__global__ void k_zero(u64* pk, int* flg) {
  int i = blockIdx.x * blockDim.x + threadIdx.x;
  if (i < 2048) pk[i] = 0ull;
  if (i < 4096) flg[i] = 0;
}

__device__ __forceinline__ float ftanh(float x) {
  x = fminf(fmaxf(x, -9.0f), 9.0f);
  float e = __expf(2.0f * x);
  return (e - 1.0f) / (e + 1.0f);
}

// Wf[((ct16*32 + kb)*64 + l)*8 + j] = W[ct16*16 + (l&15)][kb*32 + (l>>4)*8 + j]
__global__ void k_prep(const float* __restrict__ W, _Float16* __restrict__ Wf) {
  int i = blockIdx.x * blockDim.x + threadIdx.x;   // 0..131071
  int l = i & 63, kb = (i >> 6) & 31, ct = i >> 11;
  const float* src = W + (size_t)(ct * 16 + (l & 15)) * 1024 + kb * 32 + (l >> 4) * 8;
  half8v o;
#pragma unroll
  for (int j = 0; j < 8; ++j) o[j] = (_Float16)src[j];
  *(half8v*)(Wf + ((size_t)i << 3)) = o;
}

__device__ __forceinline__ f32x4 mfma(half8v a, half8v b, f32x4 c) {
  return __builtin_amdgcn_mfma_f32_16x16x32_f16(a, b, c, 0, 0, 0);
}

// One K-quarter (256) of rec[32 x 2ct]. A from 16KB swizzled quarter image;
// B from fragment-contiguous Wf; kq selects K-quarter; 2-set prefetch +
// per-CU K rotation. Accumulates into acc.
__device__ __forceinline__ void gemm_quarter(const char* Aq,
                                             const _Float16* wfW, int kq,
                                             int l, int rot, f32x4 acc[2][2]) {
  const int lr = l & 15, lk = l >> 4, r7 = l & 7;
  const char* ar0 = Aq + lr * 512;
  const char* ar1 = Aq + (16 + lr) * 512;
  const _Float16* wk = wfW + (kq << 12);
  half8v bA[2], bB[2];
  bA[0] = *(const half8v*)(wk + (rot << 9));
  bA[1] = *(const half8v*)(wk + (1 << 14) + (rot << 9));
#pragma unroll 1
  for (int it = 0; it < 8; it += 2) {
    const int k0 = (it + rot) & 7;
    const int k1 = (it + 1 + rot) & 7;
    const int k2 = (it + 2 + rot) & 7;
    half8v a00 = *(const half8v*)(ar0 + ((((k0 << 2) | lk) ^ r7) << 4));
    half8v a01 = *(const half8v*)(ar1 + ((((k0 << 2) | lk) ^ r7) << 4));
    bB[0] = *(const half8v*)(wk + (k1 << 9));
    bB[1] = *(const half8v*)(wk + (1 << 14) + (k1 << 9));
    acc[0][0] = mfma(a00, bA[0], acc[0][0]);
    acc[0][1] = mfma(a00, bA[1], acc[0][1]);
    acc[1][0] = mfma(a01, bA[0], acc[1][0]);
    acc[1][1] = mfma(a01, bA[1], acc[1][1]);
    half8v a10 = *(const half8v*)(ar0 + ((((k1 << 2) | lk) ^ r7) << 4));
    half8v a11 = *(const half8v*)(ar1 + ((((k1 << 2) | lk) ^ r7) << 4));
    bA[0] = *(const half8v*)(wk + (k2 << 9));
    bA[1] = *(const half8v*)(wk + (1 << 14) + (k2 << 9));
    acc[0][0] = mfma(a10, bB[0], acc[0][0]);
    acc[0][1] = mfma(a10, bB[1], acc[0][1]);
    acc[1][0] = mfma(a11, bB[0], acc[1][0]);
    acc[1][1] = mfma(a11, bB[1], acc[1][1]);
  }
}

// quad act-exchange + 4 K-quarter GEMMs with staging hidden under own GEMM.
__device__ __forceinline__ void exch_gemm(
    char* Ab, char* gxB, int* flg, int bid, int rg, int quarter,
    int pcnt, const _Float16* wfW, int l, int tid, int rot, f32x4 acc[2][2]) {
  __syncthreads();   // epilogue act writes visible block-wide
  {
    int off = tid * 16;
    const char* src = Ab + quarter * 16384;
    f4 v0 = *(const f4*)(src + off);
    f4 v1 = *(const f4*)(src + off + 8192);
    char* dst = gxB + (size_t)bid * 16384;
    *(f4*)(dst + off) = v0;
    *(f4*)(dst + off + 8192) = v1;
  }
  __syncthreads();   // copy stores drained before flag
  if (tid == 0) ASTI(&flg[bid * 16], pcnt);
  // poll partners now — their copies ran concurrently, flags ~already set
  if (tid < 3) {
    int pq = (quarter + 1 + tid) & 3;
    int pbid = (pq << 6) | rg;
    while (ALDI(&flg[pbid * 16]) < pcnt) __builtin_amdgcn_s_sleep(1);
  }
  __syncthreads();   // all threads know partner data is ready
  // issue all partner stagings (write partner LDS regions), then run the
  // OWN gemm (reads own LDS region — disjoint) while loads are in flight.
#pragma unroll
  for (int j = 1; j < 4; ++j) {
    int pq = (quarter + j) & 3;
    int pbid = (pq << 6) | rg;
    const char* src = gxB + (size_t)pbid * 16384;
    int off = tid * 16;
    __builtin_amdgcn_global_load_lds((const AS1 void*)(src + off),
                                     (AS3 void*)(Ab + pq * 16384 + off), 16, 0, 0);
    __builtin_amdgcn_global_load_lds((const AS1 void*)(src + off + 8192),
                                     (AS3 void*)(Ab + pq * 16384 + off + 8192), 16, 0, 0);
  }
#pragma unroll
  for (int a = 0; a < 2; ++a)
#pragma unroll
    for (int b = 0; b < 2; ++b)
#pragma unroll
      for (int q = 0; q < 4; ++q) acc[a][b][q] = 0.0f;
  gemm_quarter(Ab + quarter * 16384, wfW, quarter, l, rot, acc);
  __syncthreads();   // drains staging vmcnt; partner images complete
#pragma unroll
  for (int j = 1; j < 4; ++j) {
    int pq = (quarter + j) & 3;
    gemm_quarter(Ab + pq * 16384, wfW, pq, l, rot, acc);
  }
}

// e = rt*8 + ci*4 + qq (16 elems). Thread: row rt*16+lk4+qq, col = wv*32 +
// ci*16 + lr16 within quarter. y/ys in LDS thread-private slots.
template <int S>
__device__ __forceinline__ void stage_epi(
    const f32x4 acc[2][2], float h,
    float* yT, float* ysT, const half2v* dh,
    half2v* k1h, half2v* k2h, half2v* k3h, half2v* k4h, half2v* k5h, half2v* eh,
    const float* itau2, const float* bias2,
    char* Ab, int quarter, int wv, int l, float* errAcc) {
  const int lk4 = ((l >> 4) & 3) * 4, lr16 = l & 15;
#pragma unroll
  for (int rt = 0; rt < 2; ++rt) {
#pragma unroll
    for (int ci = 0; ci < 2; ++ci) {
#pragma unroll
      for (int qq = 0; qq < 4; ++qq) {
        const int e = rt * 8 + ci * 4 + qq;
        float yv = yT[e * NTHR];
        float ks;
        if constexpr (S == 1) {
          ks = (float)k1h[e >> 1][e & 1];
        } else {
          ks = itau2[ci] * ((float)dh[e >> 1][e & 1] + acc[rt][ci][qq] - ysT[e * NTHR]);
        }
        float nys;
        if constexpr (S == 1) {
          eh[e >> 1][e & 1] = (_Float16)(E1c * ks);
          nys = yv + h * (0.2f * ks);
        } else if constexpr (S == 2) {
          k2h[e >> 1][e & 1] = (_Float16)ks;
          float k1 = (float)k1h[e >> 1][e & 1];
          nys = yv + h * ((3.0f / 40.0f) * k1 + (9.0f / 40.0f) * ks);
        } else if constexpr (S == 3) {
          k3h[e >> 1][e & 1] = (_Float16)ks;
          eh[e >> 1][e & 1] = (_Float16)((float)eh[e >> 1][e & 1] + E3c * ks);
          float k1 = (float)k1h[e >> 1][e & 1], k2 = (float)k2h[e >> 1][e & 1];
          nys = yv + h * ((44.0f / 45.0f) * k1 + (-56.0f / 15.0f) * k2 + (32.0f / 9.0f) * ks);
        } else if constexpr (S == 4) {
          k4h[e >> 1][e & 1] = (_Float16)ks;
          eh[e >> 1][e & 1] = (_Float16)((float)eh[e >> 1][e & 1] + E4c * ks);
          float k1 = (float)k1h[e >> 1][e & 1], k2 = (float)k2h[e >> 1][e & 1];
          float k3 = (float)k3h[e >> 1][e & 1];
          nys = yv + h * ((19372.0f / 6561.0f) * k1 + (-25360.0f / 2187.0f) * k2 +
                          (64448.0f / 6561.0f) * k3 + (-212.0f / 729.0f) * ks);
        } else if constexpr (S == 5) {
          k5h[e >> 1][e & 1] = (_Float16)ks;
          eh[e >> 1][e & 1] = (_Float16)((float)eh[e >> 1][e & 1] + E5c * ks);
          float k1 = (float)k1h[e >> 1][e & 1], k2 = (float)k2h[e >> 1][e & 1];
          float k3 = (float)k3h[e >> 1][e & 1], k4 = (float)k4h[e >> 1][e & 1];
          nys = yv + h * ((9017.0f / 3168.0f) * k1 + (-355.0f / 33.0f) * k2 +
                          (46732.0f / 5247.0f) * k3 + (49.0f / 176.0f) * k4 +
                          (-5103.0f / 18656.0f) * ks);
        } else if constexpr (S == 6) {
          eh[e >> 1][e & 1] = (_Float16)((float)eh[e >> 1][e & 1] + E6c * ks);
          float k1 = (float)k1h[e >> 1][e & 1];
          float k3 = (float)k3h[e >> 1][e & 1], k4 = (float)k4h[e >> 1][e & 1];
          float k5 = (float)k5h[e >> 1][e & 1];
          nys = yv + h * ((35.0f / 384.0f) * k1 + (500.0f / 1113.0f) * k3 +
                          (125.0f / 192.0f) * k4 + (-2187.0f / 6784.0f) * k5 +
                          (11.0f / 84.0f) * ks);
        } else {  // S == 7: k7 -> k2h slot (dead after S5); error norm
          k2h[e >> 1][e & 1] = (_Float16)ks;
          float ev = h * ((float)eh[e >> 1][e & 1] + E7c * ks);
          float sc = 1e-6f + 1e-3f * fmaxf(fabsf(yv), fabsf(ysT[e * NTHR]));
          float r = ev / sc;
          *errAcc += r * r;
          nys = 0.0f;
        }
        if constexpr (S <= 6) {
          ysT[e * NTHR] = nys;
          float av = ftanh(nys + bias2[ci]);
          int rowl = rt * 16 + lk4 + qq;
          int colp = wv * 32 + ci * 16 + lr16;   // 0..255
          *(_Float16*)(Ab + quarter * 16384 + rowl * 512 +
                       ((((colp >> 3) ^ (rowl & 7)) << 4)) + (colp & 7) * 2) =
              (_Float16)av;
        }
      }
    }
  }
}

__global__ __launch_bounds__(NTHR) void k_ode(
    const float* __restrict__ inp, const float* __restrict__ prev,
    const float* __restrict__ tau, const float* __restrict__ iw,
    const float* __restrict__ bias, const _Float16* __restrict__ Wf,
    char* __restrict__ gx, float* __restrict__ out,
    u64* __restrict__ pk, int* __restrict__ flg) {
  __shared__ _Float16 actL[4][32][256];   // 64 KB: 4 quarter images
  __shared__ float yL[16 * NTHR];         // 32 KB
  __shared__ float ysL[16 * NTHR];        // 32 KB
  __shared__ float sm[256];
  __shared__ float wsum[8];
  __shared__ float bc;

  const int tid = (int)threadIdx.x, bid = (int)blockIdx.x;
  const int l = tid & 63, wv = tid >> 6;                 // 8 waves
  const int lr16 = l & 15, lk4 = ((l >> 4) & 3) * 4;
  const int rg = bid & 63;                               // rowgroup 0..63
  const int quarter = bid >> 6;                          // 0..3
  const int rbase = rg * 32;
  const int colBase = quarter * 256;
  const int rot = ((rg >> 3) + quarter * 2) & 7;         // K-phase spread
  char* Ab = (char*)&actL[0][0][0];
  float* yT = yL + tid;
  float* ysT = ysL + tid;
  const _Float16* wfW = Wf + ((size_t)(quarter * 16 + wv * 2) << 14) + (l << 3);
  char* gxB[2] = {gx, gx + (size_t)NBLK * 16384};

  // --- state init + act1 own quarter -> Ab own region ---
  half2v dh[8], k1h[8], k2h[8], k3h[8], k4h[8], k5h[8], eh[8];
  float itau2[2], bias2[2];
#pragma unroll
  for (int ci = 0; ci < 2; ++ci) {
    int col = colBase + wv * 32 + ci * 16 + lr16;
    itau2[ci] = 1.0f / tau[col];
    bias2[ci] = bias[col];
  }
#pragma unroll
  for (int rt = 0; rt < 2; ++rt)
#pragma unroll
    for (int ci = 0; ci < 2; ++ci)
#pragma unroll
      for (int qq = 0; qq < 4; ++qq) {
        const int e = rt * 8 + ci * 4 + qq;
        int rowl = rt * 16 + lk4 + qq;
        int colp = wv * 32 + ci * 16 + lr16;
        int col = colBase + colp;
        size_t off = (size_t)(rbase + rowl) * 1024 + col;
        float yv = prev[off];
        yT[e * NTHR] = yv;
        ysT[e * NTHR] = yv;
        dh[e >> 1][e & 1] = (_Float16)(inp[off] * iw[col]);
        float av = ftanh(yv + bias2[ci]);
        *(_Float16*)(Ab + quarter * 16384 + rowl * 512 +
                     ((((colp >> 3) ^ (rowl & 7)) << 4)) + (colp & 7) * 2) =
            (_Float16)av;
      }

  // --- initial k1 (exchange epoch 1) ---
  f32x4 acc[2][2];
  int pcnt = 1;
  exch_gemm(Ab, gxB[1], flg, bid, rg, quarter, pcnt, wfW, l, tid, rot, acc);
#pragma unroll
  for (int rt = 0; rt < 2; ++rt)
#pragma unroll
    for (int ci = 0; ci < 2; ++ci)
#pragma unroll
      for (int qq = 0; qq < 4; ++qq) {
        const int e = rt * 8 + ci * 4 + qq;
        k1h[e >> 1][e & 1] =
            (_Float16)(itau2[ci] * ((float)dh[e >> 1][e & 1] + acc[rt][ci][qq] - yT[e * NTHR]));
      }

  float t = 0.0f, dtv = 0.1f;
#pragma unroll 1
  for (int s = 0; s < 40; ++s) {
    if (t >= 1.0f - 1e-7f) break;
    const float h = fminf(dtv, 1.0f - t);

    stage_epi<1>(acc, h, yT, ysT, dh, k1h, k2h, k3h, k4h, k5h, eh, itau2, bias2,
                 Ab, quarter, wv, l, nullptr);
    ++pcnt; exch_gemm(Ab, gxB[pcnt & 1], flg, bid, rg, quarter, pcnt, wfW, l, tid, rot, acc);
    stage_epi<2>(acc, h, yT, ysT, dh, k1h, k2h, k3h, k4h, k5h, eh, itau2, bias2,
                 Ab, quarter, wv, l, nullptr);
    ++pcnt; exch_gemm(Ab, gxB[pcnt & 1], flg, bid, rg, quarter, pcnt, wfW, l, tid, rot, acc);
    stage_epi<3>(acc, h, yT, ysT, dh, k1h, k2h, k3h, k4h, k5h, eh, itau2, bias2,
                 Ab, quarter, wv, l, nullptr);
    ++pcnt; exch_gemm(Ab, gxB[pcnt & 1], flg, bid, rg, quarter, pcnt, wfW, l, tid, rot, acc);
    stage_epi<4>(acc, h, yT, ysT, dh, k1h, k2h, k3h, k4h, k5h, eh, itau2, bias2,
                 Ab, quarter, wv, l, nullptr);
    ++pcnt; exch_gemm(Ab, gxB[pcnt & 1], flg, bid, rg, quarter, pcnt, wfW, l, tid, rot, acc);
    stage_epi<5>(acc, h, yT, ysT, dh, k1h, k2h, k3h, k4h, k5h, eh, itau2, bias2,
                 Ab, quarter, wv, l, nullptr);
    ++pcnt; exch_gemm(Ab, gxB[pcnt & 1], flg, bid, rg, quarter, pcnt, wfW, l, tid, rot, acc);
    stage_epi<6>(acc, h, yT, ysT, dh, k1h, k2h, k3h, k4h, k5h, eh, itau2, bias2,
                 Ab, quarter, wv, l, nullptr);   // act7
    ++pcnt; exch_gemm(Ab, gxB[pcnt & 1], flg, bid, rg, quarter, pcnt, wfW, l, tid, rot, acc);
    float errAcc = 0.0f;
    stage_epi<7>(acc, h, yT, ysT, dh, k1h, k2h, k3h, k4h, k5h, eh, itau2, bias2,
                 nullptr, quarter, wv, l, &errAcc);

    // --- block partial + single packed-flag grid exchange (r9-verified) ---
#pragma unroll
    for (int o = 32; o > 0; o >>= 1) errAcc += __shfl_down(errAcc, o, 64);
    if (l == 0) wsum[wv] = errAcc;
    __syncthreads();
    float sblk = 0.0f;
    if (tid == 0) {
#pragma unroll
      for (int w = 0; w < 8; ++w) sblk += wsum[w];
    }
    const u64 ep = (u64)(s + 2);
    const int slot = (int)(ep & 1);
    if (tid == 0)
      AST64(&pk[bid * 8 + slot], (ep << 32) | (u64)__float_as_uint(sblk));
    if (tid < 256) {
      u64 v;
      do { v = ALD64(&pk[tid * 8 + slot]); } while ((v >> 32) < ep);
      sm[tid] = __uint_as_float((unsigned)v);
    }
    __syncthreads();
    if (tid < 64) {
      float a = sm[tid] + sm[tid + 64] + sm[tid + 128] + sm[tid + 192];
#pragma unroll
      for (int o = 1; o < 64; o <<= 1) a += __shfl_xor(a, o, 64);
      if (tid == 0) bc = a;
    }
    __syncthreads();
    float sd = bc;

    // --- controller (uniform in every block) + FSAL commit ---
    float enorm = fmaxf(sqrtf(sd / 2097152.0f), 1e-10f);
    if (enorm <= 1.0f) {
      t = t + h;
#pragma unroll
      for (int e = 0; e < 16; ++e) yT[e * NTHR] = ysT[e * NTHR];
#pragma unroll
      for (int i = 0; i < 8; ++i) k1h[i] = k2h[i];   // FSAL: k1 = k7
    }
    float factor = fminf(fmaxf(0.9f * powf(enorm, -0.2f), 0.2f), 5.0f);
    dtv = dtv * factor;
  }

  // --- final output ---
#pragma unroll
  for (int rt = 0; rt < 2; ++rt)
#pragma unroll
    for (int ci = 0; ci < 2; ++ci)
#pragma unroll
      for (int qq = 0; qq < 4; ++qq) {
        const int e = rt * 8 + ci * 4 + qq;
        int rowl = rt * 16 + lk4 + qq;
        int col = colBase + wv * 32 + ci * 16 + lr16;
        out[(size_t)(rbase + rowl) * 1024 + col] = yT[e * NTHR];
      }
}

extern "C" void kernel_launch(void* const* d_in, const int* in_sizes, int n_in,
                              void* d_out, int out_size, void* d_ws, size_t ws_size,
                              hipStream_t stream) {
  const float* inp = (const float*)d_in[0];
  const float* prev = (const float*)d_in[1];
  const float* tau = (const float*)d_in[2];
  const float* W = (const float*)d_in[3];
  const float* iw = (const float*)d_in[4];
  const float* bias = (const float*)d_in[5];
  float* out = (float*)d_out;

  char* ws = (char*)d_ws;
  const size_t MB = 1024 * 1024;
  u64* pk = (u64*)ws;                            // 16 KB
  int* flg = (int*)(ws + 16384);                 // 16 KB
  _Float16* Wf = (_Float16*)(ws + 64 * 1024);    // 2 MB
  char* gx = ws + 64 * 1024 + 2 * MB;            // 8 MB (2 buf x 256 x 16KB)

  k_zero<<<8, 512, 0, stream>>>(pk, flg);
  k_prep<<<512, 256, 0, stream>>>(W, Wf);
  k_ode<<<NBLK, NTHR, 0, stream>>>(inp, prev, tau, iw, bias, Wf, gx, out, pk, flg);
}

// Round 20
// 527.375 us; speedup vs baseline: 1.0723x; 1.0723x over previous
//
#include <hip/hip_runtime.h>
#include <math.h>

// CTRNN + adaptive DOPRI5 (B=2048, N=1024). Round 20 = Round 18 schedule
// (the best, 513us) with BOTH poll and staging hidden: split the own-
// quarter GEMM into two K-halves; poll after the first half (partner has
// also computed ~half a GEMM -> flag already set, spin ~0), issue the 6
// partner stagings, run the second own half (staging hides under it),
// drain, then the 3 partner GEMMs. r19's mistake (poll before own GEMM)
// reverted. All else identical to r18: 256 blocks x 512 thr, 64 rowgroups
// x 4 col-quarters, quad partners same-XCD, y/ys in LDS, k's half2 regs,
// M=32 MFMA, packed-flag err exchange, uniform controller, FSAL k1=k7.

typedef float f4 __attribute__((ext_vector_type(4)));
typedef float f32x4 __attribute__((ext_vector_type(4)));
typedef _Float16 half8v __attribute__((ext_vector_type(8)));
typedef _Float16 half2v __attribute__((ext_vector_type(2)));
typedef unsigned long long u64;

#define AS1 __attribute__((address_space(1)))
#define AS3 __attribute__((address_space(3)))

#define NBLK 256
#define NTHR 512

#define E1c (71.0f / 57600.0f)
#define E3c (-71.0f / 16695.0f)
#define E4c (71.0f / 1920.0f)
#define E5c (-17253.0f / 339200.0f)
#define E6c (22.0f / 525.0f)
#define E7c (-1.0f / 40.0f)

#define ALDI(p) __hip_atomic_load((p), __ATOMIC_ACQUIRE, __HIP_MEMORY_SCOPE_AGENT)
#define ASTI(p, v) __hip_atomic_store((p), (v), __ATOMIC_RELEASE, __HIP_MEMORY_SCOPE_AGENT)
#define ALD64(p) __hip_atomic_load((p), __ATOMIC_ACQUIRE, __HIP_MEMORY_SCOPE_AGENT)
#define AST64(p, v) __hip_atomic_store((p), (v), __ATOMIC_RELEASE, __HIP_MEMORY_SCOPE_AGENT)

__global__ void k_zero(u64* pk, int* flg) {
  int i = blockIdx.x * blockDim.x + threadIdx.x;
  if (i < 2048) pk[i] = 0ull;
  if (i < 4096) flg[i] = 0;
}

__device__ __forceinline__ float ftanh(float x) {
  x = fminf(fmaxf(x, -9.0f), 9.0f);
  float e = __expf(2.0f * x);
  return (e - 1.0f) / (e + 1.0f);
}

// Wf[((ct16*32 + kb)*64 + l)*8 + j] = W[ct16*16 + (l&15)][kb*32 + (l>>4)*8 + j]
__global__ void k_prep(const float* __restrict__ W, _Float16* __restrict__ Wf) {
  int i = blockIdx.x * blockDim.x + threadIdx.x;   // 0..131071
  int l = i & 63, kb = (i >> 6) & 31, ct = i >> 11;
  const float* src = W + (size_t)(ct * 16 + (l & 15)) * 1024 + kb * 32 + (l >> 4) * 8;
  half8v o;
#pragma unroll
  for (int j = 0; j < 8; ++j) o[j] = (_Float16)src[j];
  *(half8v*)(Wf + ((size_t)i << 3)) = o;
}

__device__ __forceinline__ f32x4 mfma(half8v a, half8v b, f32x4 c) {
  return __builtin_amdgcn_mfma_f32_16x16x32_f16(a, b, c, 0, 0, 0);
}

// K-range [it0,it1) of one K-quarter of rec[32 x 2ct]. A from 16KB
// swizzled quarter image; B from fragment-contiguous Wf; 2-set prefetch.
__device__ __forceinline__ void gemm_qr(const char* Aq, const _Float16* wfW,
                                        int kq, int l, int rot, int it0, int it1,
                                        f32x4 acc[2][2]) {
  const int lr = l & 15, lk = l >> 4, r7 = l & 7;
  const char* ar0 = Aq + lr * 512;
  const char* ar1 = Aq + (16 + lr) * 512;
  const _Float16* wk = wfW + (kq << 12);
  half8v bA[2], bB[2];
  bA[0] = *(const half8v*)(wk + (((it0 + rot) & 7) << 9));
  bA[1] = *(const half8v*)(wk + (1 << 14) + (((it0 + rot) & 7) << 9));
#pragma unroll 1
  for (int it = it0; it < it1; it += 2) {
    const int k0 = (it + rot) & 7;
    const int k1 = (it + 1 + rot) & 7;
    const int k2 = (it + 2 + rot) & 7;
    half8v a00 = *(const half8v*)(ar0 + ((((k0 << 2) | lk) ^ r7) << 4));
    half8v a01 = *(const half8v*)(ar1 + ((((k0 << 2) | lk) ^ r7) << 4));
    bB[0] = *(const half8v*)(wk + (k1 << 9));
    bB[1] = *(const half8v*)(wk + (1 << 14) + (k1 << 9));
    acc[0][0] = mfma(a00, bA[0], acc[0][0]);
    acc[0][1] = mfma(a00, bA[1], acc[0][1]);
    acc[1][0] = mfma(a01, bA[0], acc[1][0]);
    acc[1][1] = mfma(a01, bA[1], acc[1][1]);
    half8v a10 = *(const half8v*)(ar0 + ((((k1 << 2) | lk) ^ r7) << 4));
    half8v a11 = *(const half8v*)(ar1 + ((((k1 << 2) | lk) ^ r7) << 4));
    bA[0] = *(const half8v*)(wk + (k2 << 9));
    bA[1] = *(const half8v*)(wk + (1 << 14) + (k2 << 9));
    acc[0][0] = mfma(a10, bB[0], acc[0][0]);
    acc[0][1] = mfma(a10, bB[1], acc[0][1]);
    acc[1][0] = mfma(a11, bB[0], acc[1][0]);
    acc[1][1] = mfma(a11, bB[1], acc[1][1]);
  }
}

// quad act-exchange + 4 K-quarter GEMMs; poll hidden under own-GEMM half 1,
// partner staging hidden under own-GEMM half 2 (r18 order refined).
__device__ __forceinline__ void exch_gemm(
    char* Ab, char* gxB, int* flg, int bid, int rg, int quarter,
    int pcnt, const _Float16* wfW, int l, int tid, int rot, f32x4 acc[2][2]) {
  __syncthreads();   // epilogue act writes visible block-wide
  {
    int off = tid * 16;
    const char* src = Ab + quarter * 16384;
    f4 v0 = *(const f4*)(src + off);
    f4 v1 = *(const f4*)(src + off + 8192);
    char* dst = gxB + (size_t)bid * 16384;
    *(f4*)(dst + off) = v0;
    *(f4*)(dst + off + 8192) = v1;
  }
  __syncthreads();   // copy stores drained before flag
  if (tid == 0) ASTI(&flg[bid * 16], pcnt);
#pragma unroll
  for (int a = 0; a < 2; ++a)
#pragma unroll
    for (int b = 0; b < 2; ++b)
#pragma unroll
      for (int q = 0; q < 4; ++q) acc[a][b][q] = 0.0f;
  // own GEMM first half — partner blocks are doing the same concurrently
  gemm_qr(Ab + quarter * 16384, wfW, quarter, l, rot, 0, 4, acc);
  // poll now: partners have also computed ~half a GEMM -> flags set, spin~0
  if (tid < 3) {
    int pq = (quarter + 1 + tid) & 3;
    int pbid = (pq << 6) | rg;
    while (ALDI(&flg[pbid * 16]) < pcnt) __builtin_amdgcn_s_sleep(1);
  }
  __syncthreads();   // partner data known-ready block-wide
  // issue partner stagings (write partner LDS regions — disjoint from own)
#pragma unroll
  for (int j = 1; j < 4; ++j) {
    int pq = (quarter + j) & 3;
    int pbid = (pq << 6) | rg;
    const char* src = gxB + (size_t)pbid * 16384;
    int off = tid * 16;
    __builtin_amdgcn_global_load_lds((const AS1 void*)(src + off),
                                     (AS3 void*)(Ab + pq * 16384 + off), 16, 0, 0);
    __builtin_amdgcn_global_load_lds((const AS1 void*)(src + off + 8192),
                                     (AS3 void*)(Ab + pq * 16384 + off + 8192), 16, 0, 0);
  }
  // own GEMM second half — staging hides under it
  gemm_qr(Ab + quarter * 16384, wfW, quarter, l, rot, 4, 8, acc);
  __syncthreads();   // drains staging vmcnt; partner images complete
#pragma unroll
  for (int j = 1; j < 4; ++j) {
    int pq = (quarter + j) & 3;
    gemm_qr(Ab + pq * 16384, wfW, pq, l, rot, 0, 8, acc);
  }
}

// e = rt*8 + ci*4 + qq (16 elems). Thread: row rt*16+lk4+qq, col = wv*32 +
// ci*16 + lr16 within quarter. y/ys in LDS thread-private slots.
template <int S>
__device__ __forceinline__ void stage_epi(
    const f32x4 acc[2][2], float h,
    float* yT, float* ysT, const half2v* dh,
    half2v* k1h, half2v* k2h, half2v* k3h, half2v* k4h, half2v* k5h, half2v* eh,
    const float* itau2, const float* bias2,
    char* Ab, int quarter, int wv, int l, float* errAcc) {
  const int lk4 = ((l >> 4) & 3) * 4, lr16 = l & 15;
#pragma unroll
  for (int rt = 0; rt < 2; ++rt) {
#pragma unroll
    for (int ci = 0; ci < 2; ++ci) {
#pragma unroll
      for (int qq = 0; qq < 4; ++qq) {
        const int e = rt * 8 + ci * 4 + qq;
        float yv = yT[e * NTHR];
        float ks;
        if constexpr (S == 1) {
          ks = (float)k1h[e >> 1][e & 1];
        } else {
          ks = itau2[ci] * ((float)dh[e >> 1][e & 1] + acc[rt][ci][qq] - ysT[e * NTHR]);
        }
        float nys;
        if constexpr (S == 1) {
          eh[e >> 1][e & 1] = (_Float16)(E1c * ks);
          nys = yv + h * (0.2f * ks);
        } else if constexpr (S == 2) {
          k2h[e >> 1][e & 1] = (_Float16)ks;
          float k1 = (float)k1h[e >> 1][e & 1];
          nys = yv + h * ((3.0f / 40.0f) * k1 + (9.0f / 40.0f) * ks);
        } else if constexpr (S == 3) {
          k3h[e >> 1][e & 1] = (_Float16)ks;
          eh[e >> 1][e & 1] = (_Float16)((float)eh[e >> 1][e & 1] + E3c * ks);
          float k1 = (float)k1h[e >> 1][e & 1], k2 = (float)k2h[e >> 1][e & 1];
          nys = yv + h * ((44.0f / 45.0f) * k1 + (-56.0f / 15.0f) * k2 + (32.0f / 9.0f) * ks);
        } else if constexpr (S == 4) {
          k4h[e >> 1][e & 1] = (_Float16)ks;
          eh[e >> 1][e & 1] = (_Float16)((float)eh[e >> 1][e & 1] + E4c * ks);
          float k1 = (float)k1h[e >> 1][e & 1], k2 = (float)k2h[e >> 1][e & 1];
          float k3 = (float)k3h[e >> 1][e & 1];
          nys = yv + h * ((19372.0f / 6561.0f) * k1 + (-25360.0f / 2187.0f) * k2 +
                          (64448.0f / 6561.0f) * k3 + (-212.0f / 729.0f) * ks);
        } else if constexpr (S == 5) {
          k5h[e >> 1][e & 1] = (_Float16)ks;
          eh[e >> 1][e & 1] = (_Float16)((float)eh[e >> 1][e & 1] + E5c * ks);
          float k1 = (float)k1h[e >> 1][e & 1], k2 = (float)k2h[e >> 1][e & 1];
          float k3 = (float)k3h[e >> 1][e & 1], k4 = (float)k4h[e >> 1][e & 1];
          nys = yv + h * ((9017.0f / 3168.0f) * k1 + (-355.0f / 33.0f) * k2 +
                          (46732.0f / 5247.0f) * k3 + (49.0f / 176.0f) * k4 +
                          (-5103.0f / 18656.0f) * ks);
        } else if constexpr (S == 6) {
          eh[e >> 1][e & 1] = (_Float16)((float)eh[e >> 1][e & 1] + E6c * ks);
          float k1 = (float)k1h[e >> 1][e & 1];
          float k3 = (float)k3h[e >> 1][e & 1], k4 = (float)k4h[e >> 1][e & 1];
          float k5 = (float)k5h[e >> 1][e & 1];
          nys = yv + h * ((35.0f / 384.0f) * k1 + (500.0f / 1113.0f) * k3 +
                          (125.0f / 192.0f) * k4 + (-2187.0f / 6784.0f) * k5 +
                          (11.0f / 84.0f) * ks);
        } else {  // S == 7: k7 -> k2h slot (dead after S5); error norm
          k2h[e >> 1][e & 1] = (_Float16)ks;
          float ev = h * ((float)eh[e >> 1][e & 1] + E7c * ks);
          float sc = 1e-6f + 1e-3f * fmaxf(fabsf(yv), fabsf(ysT[e * NTHR]));
          float r = ev / sc;
          *errAcc += r * r;
          nys = 0.0f;
        }
        if constexpr (S <= 6) {
          ysT[e * NTHR] = nys;
          float av = ftanh(nys + bias2[ci]);
          int rowl = rt * 16 + lk4 + qq;
          int colp = wv * 32 + ci * 16 + lr16;   // 0..255
          *(_Float16*)(Ab + quarter * 16384 + rowl * 512 +
                       ((((colp >> 3) ^ (rowl & 7)) << 4)) + (colp & 7) * 2) =
              (_Float16)av;
        }
      }
    }
  }
}

__global__ __launch_bounds__(NTHR) void k_ode(
    const float* __restrict__ inp, const float* __restrict__ prev,
    const float* __restrict__ tau, const float* __restrict__ iw,
    const float* __restrict__ bias, const _Float16* __restrict__ Wf,
    char* __restrict__ gx, float* __restrict__ out,
    u64* __restrict__ pk, int* __restrict__ flg) {
  __shared__ _Float16 actL[4][32][256];   // 64 KB: 4 quarter images
  __shared__ float yL[16 * NTHR];         // 32 KB
  __shared__ float ysL[16 * NTHR];        // 32 KB
  __shared__ float sm[256];
  __shared__ float wsum[8];
  __shared__ float bc;

  const int tid = (int)threadIdx.x, bid = (int)blockIdx.x;
  const int l = tid & 63, wv = tid >> 6;                 // 8 waves
  const int lr16 = l & 15, lk4 = ((l >> 4) & 3) * 4;
  const int rg = bid & 63;                               // rowgroup 0..63
  const int quarter = bid >> 6;                          // 0..3
  const int rbase = rg * 32;
  const int colBase = quarter * 256;
  const int rot = ((rg >> 3) + quarter * 2) & 7;         // K-phase spread
  char* Ab = (char*)&actL[0][0][0];
  float* yT = yL + tid;
  float* ysT = ysL + tid;
  const _Float16* wfW = Wf + ((size_t)(quarter * 16 + wv * 2) << 14) + (l << 3);
  char* gxB[2] = {gx, gx + (size_t)NBLK * 16384};

  // --- state init + act1 own quarter -> Ab own region ---
  half2v dh[8], k1h[8], k2h[8], k3h[8], k4h[8], k5h[8], eh[8];
  float itau2[2], bias2[2];
#pragma unroll
  for (int ci = 0; ci < 2; ++ci) {
    int col = colBase + wv * 32 + ci * 16 + lr16;
    itau2[ci] = 1.0f / tau[col];
    bias2[ci] = bias[col];
  }
#pragma unroll
  for (int rt = 0; rt < 2; ++rt)
#pragma unroll
    for (int ci = 0; ci < 2; ++ci)
#pragma unroll
      for (int qq = 0; qq < 4; ++qq) {
        const int e = rt * 8 + ci * 4 + qq;
        int rowl = rt * 16 + lk4 + qq;
        int colp = wv * 32 + ci * 16 + lr16;
        int col = colBase + colp;
        size_t off = (size_t)(rbase + rowl) * 1024 + col;
        float yv = prev[off];
        yT[e * NTHR] = yv;
        ysT[e * NTHR] = yv;
        dh[e >> 1][e & 1] = (_Float16)(inp[off] * iw[col]);
        float av = ftanh(yv + bias2[ci]);
        *(_Float16*)(Ab + quarter * 16384 + rowl * 512 +
                     ((((colp >> 3) ^ (rowl & 7)) << 4)) + (colp & 7) * 2) =
            (_Float16)av;
      }

  // --- initial k1 (exchange epoch 1) ---
  f32x4 acc[2][2];
  int pcnt = 1;
  exch_gemm(Ab, gxB[1], flg, bid, rg, quarter, pcnt, wfW, l, tid, rot, acc);
#pragma unroll
  for (int rt = 0; rt < 2; ++rt)
#pragma unroll
    for (int ci = 0; ci < 2; ++ci)
#pragma unroll
      for (int qq = 0; qq < 4; ++qq) {
        const int e = rt * 8 + ci * 4 + qq;
        k1h[e >> 1][e & 1] =
            (_Float16)(itau2[ci] * ((float)dh[e >> 1][e & 1] + acc[rt][ci][qq] - yT[e * NTHR]));
      }

  float t = 0.0f, dtv = 0.1f;
#pragma unroll 1
  for (int s = 0; s < 40; ++s) {
    if (t >= 1.0f - 1e-7f) break;
    const float h = fminf(dtv, 1.0f - t);

    stage_epi<1>(acc, h, yT, ysT, dh, k1h, k2h, k3h, k4h, k5h, eh, itau2, bias2,
                 Ab, quarter, wv, l, nullptr);
    ++pcnt; exch_gemm(Ab, gxB[pcnt & 1], flg, bid, rg, quarter, pcnt, wfW, l, tid, rot, acc);
    stage_epi<2>(acc, h, yT, ysT, dh, k1h, k2h, k3h, k4h, k5h, eh, itau2, bias2,
                 Ab, quarter, wv, l, nullptr);
    ++pcnt; exch_gemm(Ab, gxB[pcnt & 1], flg, bid, rg, quarter, pcnt, wfW, l, tid, rot, acc);
    stage_epi<3>(acc, h, yT, ysT, dh, k1h, k2h, k3h, k4h, k5h, eh, itau2, bias2,
                 Ab, quarter, wv, l, nullptr);
    ++pcnt; exch_gemm(Ab, gxB[pcnt & 1], flg, bid, rg, quarter, pcnt, wfW, l, tid, rot, acc);
    stage_epi<4>(acc, h, yT, ysT, dh, k1h, k2h, k3h, k4h, k5h, eh, itau2, bias2,
                 Ab, quarter, wv, l, nullptr);
    ++pcnt; exch_gemm(Ab, gxB[pcnt & 1], flg, bid, rg, quarter, pcnt, wfW, l, tid, rot, acc);
    stage_epi<5>(acc, h, yT, ysT, dh, k1h, k2h, k3h, k4h, k5h, eh, itau2, bias2,
                 Ab, quarter, wv, l, nullptr);
    ++pcnt; exch_gemm(Ab, gxB[pcnt & 1], flg, bid, rg, quarter, pcnt, wfW, l, tid, rot, acc);
    stage_epi<6>(acc, h, yT, ysT, dh, k1h, k2h, k3h, k4h, k5h, eh, itau2, bias2,
                 Ab, quarter, wv, l, nullptr);   // act7
    ++pcnt; exch_gemm(Ab, gxB[pcnt & 1], flg, bid, rg, quarter, pcnt, wfW, l, tid, rot, acc);
    float errAcc = 0.0f;
    stage_epi<7>(acc, h, yT, ysT, dh, k1h, k2h, k3h, k4h, k5h, eh, itau2, bias2,
                 nullptr, quarter, wv, l, &errAcc);

    // --- block partial + single packed-flag grid exchange (r9-verified) ---
#pragma unroll
    for (int o = 32; o > 0; o >>= 1) errAcc += __shfl_down(errAcc, o, 64);
    if (l == 0) wsum[wv] = errAcc;
    __syncthreads();
    float sblk = 0.0f;
    if (tid == 0) {
#pragma unroll
      for (int w = 0; w < 8; ++w) sblk += wsum[w];
    }
    const u64 ep = (u64)(s + 2);
    const int slot = (int)(ep & 1);
    if (tid == 0)
      AST64(&pk[bid * 8 + slot], (ep << 32) | (u64)__float_as_uint(sblk));
    if (tid < 256) {
      u64 v;
      do { v = ALD64(&pk[tid * 8 + slot]); } while ((v >> 32) < ep);
      sm[tid] = __uint_as_float((unsigned)v);
    }
    __syncthreads();
    if (tid < 64) {
      float a = sm[tid] + sm[tid + 64] + sm[tid + 128] + sm[tid + 192];
#pragma unroll
      for (int o = 1; o < 64; o <<= 1) a += __shfl_xor(a, o, 64);
      if (tid == 0) bc = a;
    }
    __syncthreads();
    float sd = bc;

    // --- controller (uniform in every block) + FSAL commit ---
    float enorm = fmaxf(sqrtf(sd / 2097152.0f), 1e-10f);
    if (enorm <= 1.0f) {
      t = t + h;
#pragma unroll
      for (int e = 0; e < 16; ++e) yT[e * NTHR] = ysT[e * NTHR];
#pragma unroll
      for (int i = 0; i < 8; ++i) k1h[i] = k2h[i];   // FSAL: k1 = k7
    }
    float factor = fminf(fmaxf(0.9f * powf(enorm, -0.2f), 0.2f), 5.0f);
    dtv = dtv * factor;
  }

  // --- final output ---
#pragma unroll
  for (int rt = 0; rt < 2; ++rt)
#pragma unroll
    for (int ci = 0; ci < 2; ++ci)
#pragma unroll
      for (int qq = 0; qq < 4; ++qq) {
        const int e = rt * 8 + ci * 4 + qq;
        int rowl = rt * 16 + lk4 + qq;
        int col = colBase + wv * 32 + ci * 16 + lr16;
        out[(size_t)(rbase + rowl) * 1024 + col] = yT[e * NTHR];
      }
}

extern "C" void kernel_launch(void* const* d_in, const int* in_sizes, int n_in,
                              void* d_out, int out_size, void* d_ws, size_t ws_size,
                              hipStream_t stream) {
  const float* inp = (const float*)d_in[0];
  const float* prev = (const float*)d_in[1];
  const float* tau = (const float*)d_in[2];
  const float* W = (const float*)d_in[3];
  const float* iw = (const float*)d_in[4];
  const float* bias = (const float*)d_in[5];
  float* out = (float*)d_out;

  char* ws = (char*)d_ws;
  const size_t MB = 1024 * 1024;
  u64* pk = (u64*)ws;                            // 16 KB
  int* flg = (int*)(ws + 16384);                 // 16 KB
  _Float16* Wf = (_Float16*)(ws + 64 * 1024);    // 2 MB
  char* gx = ws + 64 * 1024 + 2 * MB;            // 8 MB (2 buf x 256 x 16KB)

  k_zero<<<8, 512, 0, stream>>>(pk, flg);
  k_prep<<<512, 256, 0, stream>>>(W, Wf);
  k_ode<<<NBLK, NTHR, 0, stream>>>(inp, prev, tau, iw, bias, Wf, gx, out, pk, flg);
}

// Round 21
// 512.726 us; speedup vs baseline: 1.1029x; 1.0286x over previous
//
#include <hip/hip_runtime.h>
#include <math.h>

// CTRNN + adaptive DOPRI5 (B=2048, N=1024). FINAL (= Round 18, measured
// best at 513us; r19/r20 A/B confirmed this schedule is the local optimum).
// 256 blocks x 512 thr (1 block/CU). Block = 32 rows x 256 cols: 64
// rowgroups x 4 col-quarters; quad partners pq*64+rg (same XCD).
// W per block per stage = 512 KB streamed from L2 (fragment-contiguous Wf,
// per-CU K rotation, 2-set register prefetch). act = single 64KB LDS
// buffer of 4 contiguous 16KB quarter images; gx exchange ping-pongs by
// pcnt parity with per-block release flags (poll AFTER own GEMM — the
// flag propagates during compute, so the poll is free). y/ys in LDS
// thread-private slots (no spill at 128 VGPR), k's in half2 registers,
// M=32 MFMA (acc[2][2], no duplicated rows). One packed-flag error
// exchange per step; redundant uniform controller in every block;
// FSAL k1=k7 (stage 1 GEMM-free); dead steps = uniform break.

typedef float f4 __attribute__((ext_vector_type(4)));
typedef float f32x4 __attribute__((ext_vector_type(4)));
typedef _Float16 half8v __attribute__((ext_vector_type(8)));
typedef _Float16 half2v __attribute__((ext_vector_type(2)));
typedef unsigned long long u64;

#define AS1 __attribute__((address_space(1)))
#define AS3 __attribute__((address_space(3)))

#define NBLK 256
#define NTHR 512

#define E1c (71.0f / 57600.0f)
#define E3c (-71.0f / 16695.0f)
#define E4c (71.0f / 1920.0f)
#define E5c (-17253.0f / 339200.0f)
#define E6c (22.0f / 525.0f)
#define E7c (-1.0f / 40.0f)

#define ALDI(p) __hip_atomic_load((p), __ATOMIC_ACQUIRE, __HIP_MEMORY_SCOPE_AGENT)
#define ASTI(p, v) __hip_atomic_store((p), (v), __ATOMIC_RELEASE, __HIP_MEMORY_SCOPE_AGENT)
#define ALD64(p) __hip_atomic_load((p), __ATOMIC_ACQUIRE, __HIP_MEMORY_SCOPE_AGENT)
#define AST64(p, v) __hip_atomic_store((p), (v), __ATOMIC_RELEASE, __HIP_MEMORY_SCOPE_AGENT)

__global__ void k_zero(u64* pk, int* flg) {
  int i = blockIdx.x * blockDim.x + threadIdx.x;
  if (i < 2048) pk[i] = 0ull;
  if (i < 4096) flg[i] = 0;
}

__device__ __forceinline__ float ftanh(float x) {
  x = fminf(fmaxf(x, -9.0f), 9.0f);
  float e = __expf(2.0f * x);
  return (e - 1.0f) / (e + 1.0f);
}

// Wf[((ct16*32 + kb)*64 + l)*8 + j] = W[ct16*16 + (l&15)][kb*32 + (l>>4)*8 + j]
__global__ void k_prep(const float* __restrict__ W, _Float16* __restrict__ Wf) {
  int i = blockIdx.x * blockDim.x + threadIdx.x;   // 0..131071
  int l = i & 63, kb = (i >> 6) & 31, ct = i >> 11;
  const float* src = W + (size_t)(ct * 16 + (l & 15)) * 1024 + kb * 32 + (l >> 4) * 8;
  half8v o;
#pragma unroll
  for (int j = 0; j < 8; ++j) o[j] = (_Float16)src[j];
  *(half8v*)(Wf + ((size_t)i << 3)) = o;
}

__device__ __forceinline__ f32x4 mfma(half8v a, half8v b, f32x4 c) {
  return __builtin_amdgcn_mfma_f32_16x16x32_f16(a, b, c, 0, 0, 0);
}

// One K-quarter (256) of rec[32 x 2ct]. A from 16KB swizzled quarter image
// (rows 0..31, 512B/row); B from fragment-contiguous Wf; kq selects the
// K-quarter; 2-set register prefetch + per-CU K rotation. Accumulates.
__device__ __forceinline__ void gemm_quarter(const char* Aq,
                                             const _Float16* wfW, int kq,
                                             int l, int rot, f32x4 acc[2][2]) {
  const int lr = l & 15, lk = l >> 4, r7 = l & 7;
  const char* ar0 = Aq + lr * 512;
  const char* ar1 = Aq + (16 + lr) * 512;
  const _Float16* wk = wfW + (kq << 12);
  half8v bA[2], bB[2];
  bA[0] = *(const half8v*)(wk + (rot << 9));
  bA[1] = *(const half8v*)(wk + (1 << 14) + (rot << 9));
#pragma unroll 1
  for (int it = 0; it < 8; it += 2) {
    const int k0 = (it + rot) & 7;
    const int k1 = (it + 1 + rot) & 7;
    const int k2 = (it + 2 + rot) & 7;
    half8v a00 = *(const half8v*)(ar0 + ((((k0 << 2) | lk) ^ r7) << 4));
    half8v a01 = *(const half8v*)(ar1 + ((((k0 << 2) | lk) ^ r7) << 4));
    bB[0] = *(const half8v*)(wk + (k1 << 9));
    bB[1] = *(const half8v*)(wk + (1 << 14) + (k1 << 9));
    acc[0][0] = mfma(a00, bA[0], acc[0][0]);
    acc[0][1] = mfma(a00, bA[1], acc[0][1]);
    acc[1][0] = mfma(a01, bA[0], acc[1][0]);
    acc[1][1] = mfma(a01, bA[1], acc[1][1]);
    half8v a10 = *(const half8v*)(ar0 + ((((k1 << 2) | lk) ^ r7) << 4));
    half8v a11 = *(const half8v*)(ar1 + ((((k1 << 2) | lk) ^ r7) << 4));
    bA[0] = *(const half8v*)(wk + (k2 << 9));
    bA[1] = *(const half8v*)(wk + (1 << 14) + (k2 << 9));
    acc[0][0] = mfma(a10, bB[0], acc[0][0]);
    acc[0][1] = mfma(a10, bB[1], acc[0][1]);
    acc[1][0] = mfma(a11, bB[0], acc[1][0]);
    acc[1][1] = mfma(a11, bB[1], acc[1][1]);
  }
}

// quad act-exchange + 4 K-quarter GEMMs. Ab = 4 x 16KB quarter images.
__device__ __forceinline__ void exch_gemm(
    char* Ab, char* gxB, int* flg, int bid, int rg, int quarter,
    int pcnt, const _Float16* wfW, int l, int tid, int rot, f32x4 acc[2][2]) {
  __syncthreads();   // epilogue act writes visible block-wide
  {
    int off = tid * 16;
    const char* src = Ab + quarter * 16384;
    f4 v0 = *(const f4*)(src + off);
    f4 v1 = *(const f4*)(src + off + 8192);
    char* dst = gxB + (size_t)bid * 16384;
    *(f4*)(dst + off) = v0;
    *(f4*)(dst + off + 8192) = v1;
  }
  __syncthreads();   // stores drained before flag
  if (tid == 0) ASTI(&flg[bid * 16], pcnt);
#pragma unroll
  for (int a = 0; a < 2; ++a)
#pragma unroll
    for (int b = 0; b < 2; ++b)
#pragma unroll
      for (int q = 0; q < 4; ++q) acc[a][b][q] = 0.0f;
  gemm_quarter(Ab + quarter * 16384, wfW, quarter, l, rot, acc);
  if (tid < 3) {
    int pq = (quarter + 1 + tid) & 3;
    int pbid = (pq << 6) | rg;
    while (ALDI(&flg[pbid * 16]) < pcnt) __builtin_amdgcn_s_sleep(1);
  }
  __syncthreads();
#pragma unroll
  for (int j = 1; j < 4; ++j) {
    int pq = (quarter + j) & 3;
    int pbid = (pq << 6) | rg;
    const char* src = gxB + (size_t)pbid * 16384;
    int off = tid * 16;
    __builtin_amdgcn_global_load_lds((const AS1 void*)(src + off),
                                     (AS3 void*)(Ab + pq * 16384 + off), 16, 0, 0);
    __builtin_amdgcn_global_load_lds((const AS1 void*)(src + off + 8192),
                                     (AS3 void*)(Ab + pq * 16384 + off + 8192), 16, 0, 0);
  }
  __syncthreads();   // staging drained
#pragma unroll
  for (int j = 1; j < 4; ++j) {
    int pq = (quarter + j) & 3;
    gemm_quarter(Ab + pq * 16384, wfW, pq, l, rot, acc);
  }
}

// e = rt*8 + ci*4 + qq (16 elems). Thread: row rt*16+lk4+qq, col = wv*32 +
// ci*16 + lr16 within quarter. y/ys in LDS thread-private slots.
template <int S>
__device__ __forceinline__ void stage_epi(
    const f32x4 acc[2][2], float h,
    float* yT, float* ysT, const half2v* dh,
    half2v* k1h, half2v* k2h, half2v* k3h, half2v* k4h, half2v* k5h, half2v* eh,
    const float* itau2, const float* bias2,
    char* Ab, int quarter, int wv, int l, float* errAcc) {
  const int lk4 = ((l >> 4) & 3) * 4, lr16 = l & 15;
#pragma unroll
  for (int rt = 0; rt < 2; ++rt) {
#pragma unroll
    for (int ci = 0; ci < 2; ++ci) {
#pragma unroll
      for (int qq = 0; qq < 4; ++qq) {
        const int e = rt * 8 + ci * 4 + qq;
        float yv = yT[e * NTHR];
        float ks;
        if constexpr (S == 1) {
          ks = (float)k1h[e >> 1][e & 1];
        } else {
          ks = itau2[ci] * ((float)dh[e >> 1][e & 1] + acc[rt][ci][qq] - ysT[e * NTHR]);
        }
        float nys;
        if constexpr (S == 1) {
          eh[e >> 1][e & 1] = (_Float16)(E1c * ks);
          nys = yv + h * (0.2f * ks);
        } else if constexpr (S == 2) {
          k2h[e >> 1][e & 1] = (_Float16)ks;
          float k1 = (float)k1h[e >> 1][e & 1];
          nys = yv + h * ((3.0f / 40.0f) * k1 + (9.0f / 40.0f) * ks);
        } else if constexpr (S == 3) {
          k3h[e >> 1][e & 1] = (_Float16)ks;
          eh[e >> 1][e & 1] = (_Float16)((float)eh[e >> 1][e & 1] + E3c * ks);
          float k1 = (float)k1h[e >> 1][e & 1], k2 = (float)k2h[e >> 1][e & 1];
          nys = yv + h * ((44.0f / 45.0f) * k1 + (-56.0f / 15.0f) * k2 + (32.0f / 9.0f) * ks);
        } else if constexpr (S == 4) {
          k4h[e >> 1][e & 1] = (_Float16)ks;
          eh[e >> 1][e & 1] = (_Float16)((float)eh[e >> 1][e & 1] + E4c * ks);
          float k1 = (float)k1h[e >> 1][e & 1], k2 = (float)k2h[e >> 1][e & 1];
          float k3 = (float)k3h[e >> 1][e & 1];
          nys = yv + h * ((19372.0f / 6561.0f) * k1 + (-25360.0f / 2187.0f) * k2 +
                          (64448.0f / 6561.0f) * k3 + (-212.0f / 729.0f) * ks);
        } else if constexpr (S == 5) {
          k5h[e >> 1][e & 1] = (_Float16)ks;
          eh[e >> 1][e & 1] = (_Float16)((float)eh[e >> 1][e & 1] + E5c * ks);
          float k1 = (float)k1h[e >> 1][e & 1], k2 = (float)k2h[e >> 1][e & 1];
          float k3 = (float)k3h[e >> 1][e & 1], k4 = (float)k4h[e >> 1][e & 1];
          nys = yv + h * ((9017.0f / 3168.0f) * k1 + (-355.0f / 33.0f) * k2 +
                          (46732.0f / 5247.0f) * k3 + (49.0f / 176.0f) * k4 +
                          (-5103.0f / 18656.0f) * ks);
        } else if constexpr (S == 6) {
          eh[e >> 1][e & 1] = (_Float16)((float)eh[e >> 1][e & 1] + E6c * ks);
          float k1 = (float)k1h[e >> 1][e & 1];
          float k3 = (float)k3h[e >> 1][e & 1], k4 = (float)k4h[e >> 1][e & 1];
          float k5 = (float)k5h[e >> 1][e & 1];
          nys = yv + h * ((35.0f / 384.0f) * k1 + (500.0f / 1113.0f) * k3 +
                          (125.0f / 192.0f) * k4 + (-2187.0f / 6784.0f) * k5 +
                          (11.0f / 84.0f) * ks);
        } else {  // S == 7: k7 -> k2h slot (dead after S5); error norm
          k2h[e >> 1][e & 1] = (_Float16)ks;
          float ev = h * ((float)eh[e >> 1][e & 1] + E7c * ks);
          float sc = 1e-6f + 1e-3f * fmaxf(fabsf(yv), fabsf(ysT[e * NTHR]));
          float r = ev / sc;
          *errAcc += r * r;
          nys = 0.0f;
        }
        if constexpr (S <= 6) {
          ysT[e * NTHR] = nys;
          float av = ftanh(nys + bias2[ci]);
          int rowl = rt * 16 + lk4 + qq;
          int colp = wv * 32 + ci * 16 + lr16;   // 0..255
          *(_Float16*)(Ab + quarter * 16384 + rowl * 512 +
                       ((((colp >> 3) ^ (rowl & 7)) << 4)) + (colp & 7) * 2) =
              (_Float16)av;
        }
      }
    }
  }
}

__global__ __launch_bounds__(NTHR) void k_ode(
    const float* __restrict__ inp, const float* __restrict__ prev,
    const float* __restrict__ tau, const float* __restrict__ iw,
    const float* __restrict__ bias, const _Float16* __restrict__ Wf,
    char* __restrict__ gx, float* __restrict__ out,
    u64* __restrict__ pk, int* __restrict__ flg) {
  __shared__ _Float16 actL[4][32][256];   // 64 KB: 4 quarter images
  __shared__ float yL[16 * NTHR];         // 32 KB
  __shared__ float ysL[16 * NTHR];        // 32 KB
  __shared__ float sm[256];
  __shared__ float wsum[8];
  __shared__ float bc;

  const int tid = (int)threadIdx.x, bid = (int)blockIdx.x;
  const int l = tid & 63, wv = tid >> 6;                 // 8 waves
  const int lr16 = l & 15, lk4 = ((l >> 4) & 3) * 4;
  const int rg = bid & 63;                               // rowgroup 0..63
  const int quarter = bid >> 6;                          // 0..3
  const int rbase = rg * 32;
  const int colBase = quarter * 256;
  const int rot = ((rg >> 3) + quarter * 2) & 7;         // K-phase spread
  char* Ab = (char*)&actL[0][0][0];
  float* yT = yL + tid;
  float* ysT = ysL + tid;
  const _Float16* wfW = Wf + ((size_t)(quarter * 16 + wv * 2) << 14) + (l << 3);
  char* gxB[2] = {gx, gx + (size_t)NBLK * 16384};

  // --- state init + act1 own quarter -> Ab own region ---
  half2v dh[8], k1h[8], k2h[8], k3h[8], k4h[8], k5h[8], eh[8];
  float itau2[2], bias2[2];
#pragma unroll
  for (int ci = 0; ci < 2; ++ci) {
    int col = colBase + wv * 32 + ci * 16 + lr16;
    itau2[ci] = 1.0f / tau[col];
    bias2[ci] = bias[col];
  }
#pragma unroll
  for (int rt = 0; rt < 2; ++rt)
#pragma unroll
    for (int ci = 0; ci < 2; ++ci)
#pragma unroll
      for (int qq = 0; qq < 4; ++qq) {
        const int e = rt * 8 + ci * 4 + qq;
        int rowl = rt * 16 + lk4 + qq;
        int colp = wv * 32 + ci * 16 + lr16;
        int col = colBase + colp;
        size_t off = (size_t)(rbase + rowl) * 1024 + col;
        float yv = prev[off];
        yT[e * NTHR] = yv;
        ysT[e * NTHR] = yv;
        dh[e >> 1][e & 1] = (_Float16)(inp[off] * iw[col]);
        float av = ftanh(yv + bias2[ci]);
        *(_Float16*)(Ab + quarter * 16384 + rowl * 512 +
                     ((((colp >> 3) ^ (rowl & 7)) << 4)) + (colp & 7) * 2) =
            (_Float16)av;
      }

  // --- initial k1 (exchange epoch 1) ---
  f32x4 acc[2][2];
  int pcnt = 1;
  exch_gemm(Ab, gxB[1], flg, bid, rg, quarter, pcnt, wfW, l, tid, rot, acc);
#pragma unroll
  for (int rt = 0; rt < 2; ++rt)
#pragma unroll
    for (int ci = 0; ci < 2; ++ci)
#pragma unroll
      for (int qq = 0; qq < 4; ++qq) {
        const int e = rt * 8 + ci * 4 + qq;
        k1h[e >> 1][e & 1] =
            (_Float16)(itau2[ci] * ((float)dh[e >> 1][e & 1] + acc[rt][ci][qq] - yT[e * NTHR]));
      }

  float t = 0.0f, dtv = 0.1f;
#pragma unroll 1
  for (int s = 0; s < 40; ++s) {
    if (t >= 1.0f - 1e-7f) break;
    const float h = fminf(dtv, 1.0f - t);

    stage_epi<1>(acc, h, yT, ysT, dh, k1h, k2h, k3h, k4h, k5h, eh, itau2, bias2,
                 Ab, quarter, wv, l, nullptr);
    ++pcnt; exch_gemm(Ab, gxB[pcnt & 1], flg, bid, rg, quarter, pcnt, wfW, l, tid, rot, acc);
    stage_epi<2>(acc, h, yT, ysT, dh, k1h, k2h, k3h, k4h, k5h, eh, itau2, bias2,
                 Ab, quarter, wv, l, nullptr);
    ++pcnt; exch_gemm(Ab, gxB[pcnt & 1], flg, bid, rg, quarter, pcnt, wfW, l, tid, rot, acc);
    stage_epi<3>(acc, h, yT, ysT, dh, k1h, k2h, k3h, k4h, k5h, eh, itau2, bias2,
                 Ab, quarter, wv, l, nullptr);
    ++pcnt; exch_gemm(Ab, gxB[pcnt & 1], flg, bid, rg, quarter, pcnt, wfW, l, tid, rot, acc);
    stage_epi<4>(acc, h, yT, ysT, dh, k1h, k2h, k3h, k4h, k5h, eh, itau2, bias2,
                 Ab, quarter, wv, l, nullptr);
    ++pcnt; exch_gemm(Ab, gxB[pcnt & 1], flg, bid, rg, quarter, pcnt, wfW, l, tid, rot, acc);
    stage_epi<5>(acc, h, yT, ysT, dh, k1h, k2h, k3h, k4h, k5h, eh, itau2, bias2,
                 Ab, quarter, wv, l, nullptr);
    ++pcnt; exch_gemm(Ab, gxB[pcnt & 1], flg, bid, rg, quarter, pcnt, wfW, l, tid, rot, acc);
    stage_epi<6>(acc, h, yT, ysT, dh, k1h, k2h, k3h, k4h, k5h, eh, itau2, bias2,
                 Ab, quarter, wv, l, nullptr);   // act7
    ++pcnt; exch_gemm(Ab, gxB[pcnt & 1], flg, bid, rg, quarter, pcnt, wfW, l, tid, rot, acc);
    float errAcc = 0.0f;
    stage_epi<7>(acc, h, yT, ysT, dh, k1h, k2h, k3h, k4h, k5h, eh, itau2, bias2,
                 nullptr, quarter, wv, l, &errAcc);

    // --- block partial + single packed-flag grid exchange (r9-verified) ---
#pragma unroll
    for (int o = 32; o > 0; o >>= 1) errAcc += __shfl_down(errAcc, o, 64);
    if (l == 0) wsum[wv] = errAcc;
    __syncthreads();
    float sblk = 0.0f;
    if (tid == 0) {
#pragma unroll
      for (int w = 0; w < 8; ++w) sblk += wsum[w];
    }
    const u64 ep = (u64)(s + 2);
    const int slot = (int)(ep & 1);
    if (tid == 0)
      AST64(&pk[bid * 8 + slot], (ep << 32) | (u64)__float_as_uint(sblk));
    if (tid < 256) {
      u64 v;
      do { v = ALD64(&pk[tid * 8 + slot]); } while ((v >> 32) < ep);
      sm[tid] = __uint_as_float((unsigned)v);
    }
    __syncthreads();
    if (tid < 64) {
      float a = sm[tid] + sm[tid + 64] + sm[tid + 128] + sm[tid + 192];
#pragma unroll
      for (int o = 1; o < 64; o <<= 1) a += __shfl_xor(a, o, 64);
      if (tid == 0) bc = a;
    }
    __syncthreads();
    float sd = bc;

    // --- controller (uniform in every block) + FSAL commit ---
    float enorm = fmaxf(sqrtf(sd / 2097152.0f), 1e-10f);
    if (enorm <= 1.0f) {
      t = t + h;
#pragma unroll
      for (int e = 0; e < 16; ++e) yT[e * NTHR] = ysT[e * NTHR];
#pragma unroll
      for (int i = 0; i < 8; ++i) k1h[i] = k2h[i];   // FSAL: k1 = k7
    }
    float factor = fminf(fmaxf(0.9f * powf(enorm, -0.2f), 0.2f), 5.0f);
    dtv = dtv * factor;
  }

  // --- final output ---
#pragma unroll
  for (int rt = 0; rt < 2; ++rt)
#pragma unroll
    for (int ci = 0; ci < 2; ++ci)
#pragma unroll
      for (int qq = 0; qq < 4; ++qq) {
        const int e = rt * 8 + ci * 4 + qq;
        int rowl = rt * 16 + lk4 + qq;
        int col = colBase + wv * 32 + ci * 16 + lr16;
        out[(size_t)(rbase + rowl) * 1024 + col] = yT[e * NTHR];
      }
}

extern "C" void kernel_launch(void* const* d_in, const int* in_sizes, int n_in,
                              void* d_out, int out_size, void* d_ws, size_t ws_size,
                              hipStream_t stream) {
  const float* inp = (const float*)d_in[0];
  const float* prev = (const float*)d_in[1];
  const float* tau = (const float*)d_in[2];
  const float* W = (const float*)d_in[3];
  const float* iw = (const float*)d_in[4];
  const float* bias = (const float*)d_in[5];
  float* out = (float*)d_out;

  char* ws = (char*)d_ws;
  const size_t MB = 1024 * 1024;
  u64* pk = (u64*)ws;                            // 16 KB
  int* flg = (int*)(ws + 16384);                 // 16 KB
  _Float16* Wf = (_Float16*)(ws + 64 * 1024);    // 2 MB
  char* gx = ws + 64 * 1024 + 2 * MB;            // 8 MB (2 buf x 256 x 16KB)

  k_zero<<<8, 512, 0, stream>>>(pk, flg);
  k_prep<<<512, 256, 0, stream>>>(W, Wf);
  k_ode<<<NBLK, NTHR, 0, stream>>>(inp, prev, tau, iw, bias, Wf, gx, out, pk, flg);
}